// Round 3
// baseline (1995.192 us; speedup 1.0000x reference)
//
#include <hip/hip_runtime.h>
#include <cstddef>
#include <cstdint>

// Model dims
#define BB   4
#define TS   1024
#define DM   1024
#define DFF  4096
#define NHD  16
#define HDM  64
#define NLY  4
#define TOKD 256
#define POSD 768

typedef __bf16 bf16_t;
typedef __bf16 bf16x4 __attribute__((ext_vector_type(4)));
typedef __bf16 bf16x8 __attribute__((ext_vector_type(8)));
typedef float  f32x4  __attribute__((ext_vector_type(4)));

#define GLOAD_LDS16(gp, lp)                                                  \
  __builtin_amdgcn_global_load_lds(                                          \
      (const __attribute__((address_space(1))) void*)(gp),                   \
      (__attribute__((address_space(3))) void*)(lp), 16, 0, 0)

__device__ __forceinline__ float gelu_f(float x) {
  float x3 = x * x * x;
  return 0.5f * x * (1.0f + tanhf(0.7978845608028654f * (x + 0.044715f * x3)));
}

// h[b,t,:] = [tok_emb[x_in[b,t]], pos_emb[t]] -> bf16. 4 elems/thread.
__global__ __launch_bounds__(256) void k_embed(const int* __restrict__ x,
    const float* __restrict__ tok, const float* __restrict__ pos,
    bf16_t* __restrict__ h) {
  int idx = (blockIdx.x * 256 + threadIdx.x) * 4;
  int d  = idx & (DM - 1);
  int bt = idx >> 10;
  int t  = bt & (TS - 1);
  int b  = bt >> 10;
  float4 v;
  if (d < TOKD) {
    int tk = (t == 0) ? 1 : x[b * TS + t - 1];
    v = *(const float4*)(tok + tk * TOKD + d);
  } else {
    v = *(const float4*)(pos + (size_t)t * POSD + (d - TOKD));
  }
  bf16x4 o = { (bf16_t)v.x, (bf16_t)v.y, (bf16_t)v.z, (bf16_t)v.w };
  *(bf16x4*)(h + idx) = o;
}

// LayerNorm, one wave per 1024-dim row, bf16 in, bf16 out(s) (either may be
// null). fp32 statistics. Lane owns 16 contiguous elems.
__global__ __launch_bounds__(256) void k_ln(const bf16_t* __restrict__ in,
    const float* __restrict__ g, const float* __restrict__ bta,
    bf16_t* __restrict__ out1, bf16_t* __restrict__ out2) {
  int row  = blockIdx.x * 4 + (threadIdx.x >> 6);
  int lane = threadIdx.x & 63;
  const bf16_t* p = in + (size_t)row * DM + lane * 16;
  bf16x8 v0 = *(const bf16x8*)p;
  bf16x8 v1 = *(const bf16x8*)(p + 8);
  float vals[16];
  float s = 0.f, s2 = 0.f;
#pragma unroll
  for (int i = 0; i < 8; i++) { vals[i] = (float)v0[i]; vals[8 + i] = (float)v1[i]; }
#pragma unroll
  for (int i = 0; i < 16; i++) { s += vals[i]; s2 += vals[i] * vals[i]; }
#pragma unroll
  for (int off = 32; off; off >>= 1) {
    s  += __shfl_xor(s, off);
    s2 += __shfl_xor(s2, off);
  }
  float mu  = s * (1.f / DM);
  float var = s2 * (1.f / DM) - mu * mu;
  float rs  = rsqrtf(var + 1e-5f);
  bf16x8 o0, o1;
#pragma unroll
  for (int i = 0; i < 16; i++) {
    int d = lane * 16 + i;
    float v = (vals[i] - mu) * rs * g[d] + bta[d];
    if (i < 8) o0[i] = (bf16_t)v; else o1[i - 8] = (bf16_t)v;
  }
  size_t off = (size_t)row * DM + lane * 16;
  if (out1) { *(bf16x8*)(out1 + off) = o0; *(bf16x8*)(out1 + off + 8) = o1; }
  if (out2) { *(bf16x8*)(out2 + off) = o0; *(bf16x8*)(out2 + off + 8) = o1; }
}

// MFMA bf16 GEMM: C[M,N] = epi(A[M,K] * B[N,K]^T + bias[N])
// A: bf16, row stride K, staged via global_load_lds w=16.
// B: fp32 weights, row stride ldb, staged+converted to bf16 in LDS.
// C: bf16, row stride N. ACC: C += (read-modify-write, bf16 round).
// 128xTN tile / 256 threads / 4 waves (2x2 of 64x(TN/2)), BK=32, 16x16x32.
//
// T3/T4 pipeline (counted vmcnt, never 0 in steady state):
//   3 LDS buffers, loads issued 2 k-tiles ahead. Per iter t:
//     issue G(t+2)  [2 gload_lds A + NJ float4 B -> regs]
//     s_waitcnt vmcnt(GOPS)          -> G(t+1) landed (A in LDS, B in regs)
//     cvt+ds_write B(t+1)            -> Bs[(t+1)%3]
//     ds_read + 4*NJ MFMA on buf t%3
//     s_waitcnt lgkmcnt(0); s_barrier  (raw barrier: does NOT drain vmcnt)
//   Hazards: buf (t+2)%3 targeted by DMA was last read at iter t-1, whose
//   reads drained (lgkmcnt) before that iter's barrier; ds_write target
//   (t+1)%3 last read at iter t-2 (2 barriers back). B-reg slots alternate
//   per group parity; loop unrolled x2 for static reg indexing (rule #20).
//   nt = K/32 is even and >= 2 for all shapes used here.
template <bool GELU, bool ACC, int TN>
__global__ __launch_bounds__(256) void k_gemm(
    const bf16_t* __restrict__ A, const float* __restrict__ B,
    const float* __restrict__ bias, bf16_t* __restrict__ C,
    int M, int N, int K, int ldb) {
  constexpr int NJ   = TN / 32;   // 16-wide fragments per wave (4 or 2)
  constexpr int GOPS = 2 + NJ;    // vmem ops per k-tile group
  __shared__ __align__(16) bf16_t As[3][128 * 32];
  __shared__ __align__(16) bf16_t Bs[3][TN * 32];
  const int tid  = threadIdx.x;
  const int wave = tid >> 6, lane = tid & 63;
  const int m0 = blockIdx.y * 128, n0 = blockIdx.x * TN;
  const int wm = (wave >> 1) * 64, wn = (wave & 1) * (TN / 2);
  f32x4 acc[4][NJ];
#pragma unroll
  for (int i = 0; i < 4; i++)
#pragma unroll
    for (int j = 0; j < NJ; j++) acc[i][j] = {0.f, 0.f, 0.f, 0.f};

  // A staging: wave owns 16 rows/issue; DMA lane->16B rule gives [16,32] tile
  const int srow = wave * 16 + (lane >> 2);
  const int scol = (lane & 3) * 8;
  const bf16_t* Ag = A + (size_t)(m0 + srow) * K + scol;
  const int aw0 = wave * 16 * 32;
  const int aw1 = (64 + wave * 16) * 32;
  // B staging (fp32 -> bf16): thread covers rows {tid>>3 + 32i}, 4 cols
  const int brow = tid >> 3;
  const int bcol = (tid & 7) * 4;
  const float* Bg = B + (size_t)(n0 + brow) * ldb + bcol;
  const int fr = lane & 15, fq = lane >> 4;
  const int nt = K >> 5;

  float4 br0[NJ], br1[NJ];

#define ISSUE_A(g) do { const int _k = (g) << 5; const int _b = (g) % 3;     \
    GLOAD_LDS16(Ag + _k, &As[_b][aw0]);                                      \
    GLOAD_LDS16(Ag + (size_t)64 * K + _k, &As[_b][aw1]); } while (0)
#define LOAD_B(g, br) do { const int _k = (g) << 5;                          \
    _Pragma("unroll")                                                        \
    for (int _i = 0; _i < NJ; _i++)                                          \
      br[_i] = *(const float4*)(Bg + (size_t)(_i * 32) * ldb + _k); } while (0)
#define WRITE_B(g, br) do { const int _b = (g) % 3;                          \
    _Pragma("unroll")                                                        \
    for (int _i = 0; _i < NJ; _i++) {                                        \
      bf16x4 _o = { (bf16_t)br[_i].x, (bf16_t)br[_i].y,                      \
                    (bf16_t)br[_i].z, (bf16_t)br[_i].w };                    \
      *(bf16x4*)&Bs[_b][(brow + _i * 32) * 32 + bcol] = _o; } } while (0)
#define COMPUTE(g) do { const int _b = (g) % 3;                              \
    bf16x8 _af[4], _bf[NJ];                                                  \
    _Pragma("unroll")                                                        \
    for (int _i = 0; _i < 4; _i++)                                           \
      _af[_i] = *(const bf16x8*)&As[_b][(wm + _i * 16 + fr) * 32 + fq * 8];  \
    _Pragma("unroll")                                                        \
    for (int _j = 0; _j < NJ; _j++)                                          \
      _bf[_j] = *(const bf16x8*)&Bs[_b][(wn + _j * 16 + fr) * 32 + fq * 8];  \
    _Pragma("unroll")                                                        \
    for (int _i = 0; _i < 4; _i++)                                           \
      _Pragma("unroll")                                                      \
      for (int _j = 0; _j < NJ; _j++)                                        \
        acc[_i][_j] = __builtin_amdgcn_mfma_f32_16x16x32_bf16(               \
            _af[_i], _bf[_j], acc[_i][_j], 0, 0, 0); } while (0)
#define WAITV(n) asm volatile("s_waitcnt vmcnt(%0)" :: "n"(n) : "memory")
#define KBAR() do { asm volatile("s_waitcnt lgkmcnt(0)" ::: "memory");       \
                    __builtin_amdgcn_s_barrier(); } while (0)

  // ---- prologue: groups 0,1 in flight; B(0) committed ----
  ISSUE_A(0); LOAD_B(0, br0);
  ISSUE_A(1); LOAD_B(1, br1);
  WAITV(GOPS);                 // group 0 landed
  WRITE_B(0, br0);
  KBAR();

  for (int t = 0; t < nt - 2; t += 2) {
    // iter t (even)
    ISSUE_A(t + 2); LOAD_B(t + 2, br0);
    WAITV(GOPS);               // group t+1 landed
    WRITE_B(t + 1, br1);
    COMPUTE(t);
    KBAR();
    // iter t+1 (odd)
    ISSUE_A(t + 3); LOAD_B(t + 3, br1);
    WAITV(GOPS);               // group t+2 landed
    WRITE_B(t + 2, br0);
    COMPUTE(t + 1);
    KBAR();
  }
  // ---- epilogue: iters nt-2, nt-1 (only G(nt-1) still in flight) ----
  WAITV(0);
  WRITE_B(nt - 1, br1);
  COMPUTE(nt - 2);
  KBAR();
  COMPUTE(nt - 1);

#undef ISSUE_A
#undef LOAD_B
#undef WRITE_B
#undef COMPUTE
#undef WAITV
#undef KBAR

  // epilogue: C/D layout col = lane&15, row = (lane>>4)*4 + reg  [m89]
#pragma unroll
  for (int i = 0; i < 4; i++) {
#pragma unroll
    for (int j = 0; j < NJ; j++) {
#pragma unroll
      for (int r = 0; r < 4; r++) {
        int m = m0 + wm + i * 16 + fq * 4 + r;
        int n = n0 + wn + j * 16 + fr;
        float v = acc[i][j][r];
        if (bias) v += bias[n];
        if (GELU) v = gelu_f(v);
        size_t off = (size_t)m * N + n;
        if (ACC) C[off] = (bf16_t)((float)C[off] + v);
        else     C[off] = (bf16_t)v;
      }
    }
  }
}

// MFMA flash attention. qkv bf16 [2*TS, 3*DM] (2 batches); hres (bf16) += attn.
// Grid (head, q-tile, batch-in-group). Wave w owns q-rows w*16..+15.
// Per 64-wide K-tile: QK^T (8 mfma/wave), online softmax in C-layout regs,
// P->bf16 via LDS (C->A layout round trip), PV (8 mfma/wave). V staged
// transposed. LDS stride 72 breaks bank degeneracy.
__global__ __launch_bounds__(256) void k_flash(const bf16_t* __restrict__ qkv,
                                               bf16_t* __restrict__ hres) {
  __shared__ __align__(16) bf16_t Qs[64 * 72];   // re-used as P after Q->regs
  __shared__ __align__(16) bf16_t Ks[64 * 72];
  __shared__ __align__(16) bf16_t Vt[64 * 72];   // [dim][s]
  const int hh = blockIdx.x, qt = blockIdx.y, bz = blockIdx.z;
  const int tid = threadIdx.x;
  const int w = tid >> 6, lane = tid & 63;
  const int fr = lane & 15, fq = lane >> 4;
  const int sr = tid >> 2, seg = tid & 3;
  const bf16_t* base = qkv + (size_t)bz * TS * (3 * DM) + hh * HDM;
  bf16_t* Ps = Qs;

  {
    const bf16_t* qrow = base + (size_t)(qt * 64 + sr) * (3 * DM) + seg * 16;
    *(bf16x8*)&Qs[sr * 72 + seg * 16]     = *(const bf16x8*)qrow;
    *(bf16x8*)&Qs[sr * 72 + seg * 16 + 8] = *(const bf16x8*)(qrow + 8);
  }
  __syncthreads();
  bf16x8 aq[2];
  aq[0] = *(const bf16x8*)&Qs[(w * 16 + fr) * 72 + fq * 8];
  aq[1] = *(const bf16x8*)&Qs[(w * 16 + fr) * 72 + 32 + fq * 8];

  f32x4 o[4];
#pragma unroll
  for (int d = 0; d < 4; d++) o[d] = {0.f, 0.f, 0.f, 0.f};
  float mval[4] = {-1e30f, -1e30f, -1e30f, -1e30f};
  float lsum[4] = {0.f, 0.f, 0.f, 0.f};

  for (int st = 0; st <= qt; st++) {
    __syncthreads();
    {
      size_t rowoff = (size_t)(st * 64 + sr) * (3 * DM);
      const bf16_t* krow = base + rowoff + DM + seg * 16;
      *(bf16x8*)&Ks[sr * 72 + seg * 16]     = *(const bf16x8*)krow;
      *(bf16x8*)&Ks[sr * 72 + seg * 16 + 8] = *(const bf16x8*)(krow + 8);
      const bf16_t* vrow = base + rowoff + 2 * DM + seg * 16;
      bf16x8 v0 = *(const bf16x8*)vrow;
      bf16x8 v1 = *(const bf16x8*)(vrow + 8);
#pragma unroll
      for (int j = 0; j < 8; j++) Vt[(seg * 16 + j) * 72 + sr]     = v0[j];
#pragma unroll
      for (int j = 0; j < 8; j++) Vt[(seg * 16 + 8 + j) * 72 + sr] = v1[j];
    }
    __syncthreads();
    f32x4 sacc[4];
#pragma unroll
    for (int j = 0; j < 4; j++) sacc[j] = {0.f, 0.f, 0.f, 0.f};
#pragma unroll
    for (int j = 0; j < 4; j++)
#pragma unroll
      for (int hf = 0; hf < 2; hf++) {
        bf16x8 bk = *(const bf16x8*)&Ks[(j * 16 + fr) * 72 + hf * 32 + fq * 8];
        sacc[j] = __builtin_amdgcn_mfma_f32_16x16x32_bf16(aq[hf], bk, sacc[j],
                                                          0, 0, 0);
      }
#pragma unroll
    for (int j = 0; j < 4; j++)
#pragma unroll
      for (int r = 0; r < 4; r++) {
        float s = sacc[j][r] * 0.125f;
        if (st == qt && (j * 16 + fr) > (w * 16 + fq * 4 + r)) s = -1e30f;
        sacc[j][r] = s;
      }
    float corr[4];
#pragma unroll
    for (int r = 0; r < 4; r++) {
      float v = fmaxf(fmaxf(sacc[0][r], sacc[1][r]),
                      fmaxf(sacc[2][r], sacc[3][r]));
      v = fmaxf(v, __shfl_xor(v, 1));
      v = fmaxf(v, __shfl_xor(v, 2));
      v = fmaxf(v, __shfl_xor(v, 4));
      v = fmaxf(v, __shfl_xor(v, 8));
      float mn = fmaxf(mval[r], v);
      corr[r] = __expf(mval[r] - mn);
      mval[r] = mn;
      lsum[r] *= corr[r];
    }
#pragma unroll
    for (int d = 0; d < 4; d++)
#pragma unroll
      for (int r = 0; r < 4; r++) o[d][r] *= corr[r];
    float rsum[4] = {0.f, 0.f, 0.f, 0.f};
#pragma unroll
    for (int j = 0; j < 4; j++)
#pragma unroll
      for (int r = 0; r < 4; r++) {
        float p = __expf(sacc[j][r] - mval[r]);
        rsum[r] += p;
        Ps[(w * 16 + fq * 4 + r) * 72 + j * 16 + fr] = (bf16_t)p;
      }
#pragma unroll
    for (int r = 0; r < 4; r++) {
      float v = rsum[r];
      v += __shfl_xor(v, 1);
      v += __shfl_xor(v, 2);
      v += __shfl_xor(v, 4);
      v += __shfl_xor(v, 8);
      lsum[r] += v;
    }
    __syncthreads();
    bf16x8 ap[2];
    ap[0] = *(const bf16x8*)&Ps[(w * 16 + fr) * 72 + fq * 8];
    ap[1] = *(const bf16x8*)&Ps[(w * 16 + fr) * 72 + 32 + fq * 8];
#pragma unroll
    for (int d = 0; d < 4; d++)
#pragma unroll
      for (int hf = 0; hf < 2; hf++) {
        bf16x8 bv = *(const bf16x8*)&Vt[(d * 16 + fr) * 72 + hf * 32 + fq * 8];
        o[d] = __builtin_amdgcn_mfma_f32_16x16x32_bf16(ap[hf], bv, o[d],
                                                       0, 0, 0);
      }
  }
#pragma unroll
  for (int r = 0; r < 4; r++) {
    float inv = 1.0f / lsum[r];
    bf16_t* row = hres + (size_t)bz * TS * DM +
                  (size_t)(qt * 64 + w * 16 + fq * 4 + r) * DM + hh * HDM;
#pragma unroll
    for (int d = 0; d < 4; d++) {
      int c = d * 16 + fr;
      row[c] = (bf16_t)((float)row[c] + o[d][r] * inv);
    }
  }
}

// logits (M=2) + log_softmax, one wave per token row, bf16 h
__global__ __launch_bounds__(256) void k_logits(const bf16_t* __restrict__ h,
    const float* __restrict__ w, const float* __restrict__ bz,
    float* __restrict__ out) {
  int row  = blockIdx.x * 4 + (threadIdx.x >> 6);
  int lane = threadIdx.x & 63;
  const bf16_t* hp = h + (size_t)row * DM + lane * 16;
  bf16x8 a0 = *(const bf16x8*)hp;
  bf16x8 a1 = *(const bf16x8*)(hp + 8);
  float s0 = 0.f, s1 = 0.f;
#pragma unroll
  for (int i = 0; i < 16; i++) {
    float v = (float)(i < 8 ? a0[i] : a1[i - 8]);
    int d = lane * 16 + i;
    s0 += v * w[d];
    s1 += v * w[DM + d];
  }
#pragma unroll
  for (int off = 32; off; off >>= 1) {
    s0 += __shfl_xor(s0, off);
    s1 += __shfl_xor(s1, off);
  }
  if (lane == 0) {
    float z0 = s0 + bz[0], z1 = s1 + bz[1];
    float mx  = fmaxf(z0, z1);
    float lse = mx + logf(expf(z0 - mx) + expf(z1 - mx));
    out[row * 2]     = z0 - lse;
    out[row * 2 + 1] = z1 - lse;
  }
}

extern "C" void kernel_launch(void* const* d_in, const int* in_sizes, int n_in,
                              void* d_out, int out_size, void* d_ws, size_t ws_size,
                              hipStream_t stream) {
  const int*   x     = (const int*)d_in[0];
  const float* tokE  = (const float*)d_in[1];
  const float* posE  = (const float*)d_in[2];
  const float* w_qkv = (const float*)d_in[3];
  const float* b_qkv = (const float*)d_in[4];
  const float* ln1g  = (const float*)d_in[5];
  const float* ln1b  = (const float*)d_in[6];
  const float* ln2g  = (const float*)d_in[7];
  const float* ln2b  = (const float*)d_in[8];
  const float* fw1   = (const float*)d_in[9];
  const float* fb1   = (const float*)d_in[10];
  const float* fw2   = (const float*)d_in[11];
  const float* fb2   = (const float*)d_in[12];
  const float* outw  = (const float*)d_in[13];
  const float* outb  = (const float*)d_in[14];
  float* out = (float*)d_out;

  const size_t NT = (size_t)BB * TS;  // 4096 tokens
  const size_t MB = 1024 * 1024;
  // Workspace: 32 MB total.
  //   h_bf  [0, 8M):  bf16 residual stream [4096, 1024]
  //   S = [8M, 32M) 24 MB, time-shared:
  //     attn phase (per 2-batch group): a_bf [0,4M) | qkv_bf [4M,16M)
  //     ff phase: a2_bf [0,8M) pristine LN2 | f1_bf [8M,24M) (slab 2048)
  bf16_t* h_bf = (bf16_t*)d_ws;
  char*   S    = (char*)d_ws + 8 * MB;
  bf16_t* a_bf   = (bf16_t*)S;
  bf16_t* qkv_bf = (bf16_t*)(S + 4 * MB);
  bf16_t* a2_bf  = (bf16_t*)S;
  bf16_t* f1_bf  = (bf16_t*)(S + 8 * MB);

  k_embed<<<(NT * DM) / 1024, 256, 0, stream>>>(x, tokE, posE, h_bf);
  for (int l = 0; l < NLY; l++) {
    // --- attention, 2-batch groups (M=2048 QKV GEMM) ---
    for (int g = 0; g < 2; g++) {
      bf16_t* hg = h_bf + (size_t)g * 2 * TS * DM;
      k_ln<<<2 * TS / 4, 256, 0, stream>>>(hg, ln1g + l * DM, ln1b + l * DM,
                                           a_bf, nullptr);
      // TN=64: grid 48x16 = 768 blocks = 3 blocks/CU
      k_gemm<false, false, 64><<<dim3(3 * DM / 64, 2 * TS / 128), 256, 0, stream>>>(
          a_bf, w_qkv + (size_t)l * 3 * DM * DM, b_qkv + l * 3 * DM, qkv_bf,
          2 * TS, 3 * DM, DM, DM);
      k_flash<<<dim3(NHD, TS / 64, 2), 256, 0, stream>>>(qkv_bf, hg);
    }
    // --- ln2: in-place into h_bf (residual basis) + pristine copy a2_bf ---
    k_ln<<<NT / 4, 256, 0, stream>>>(h_bf, ln2g + l * DM, ln2b + l * DM,
                                     h_bf, a2_bf);
    // --- FF: 2 slabs of 2048 over DFF; FF1 reads pristine a2_bf,
    //     FF2 accumulates into h_bf (bias on slab 0 only) ---
    for (int s = 0; s < 2; s++) {
      // FF1 TN=128: grid 16x32 = 512 blocks = 2/CU
      k_gemm<true, false, 128><<<dim3(2048 / 128, NT / 128), 256, 0, stream>>>(
          a2_bf, fw1 + (size_t)l * DFF * DM + (size_t)s * 2048 * DM,
          fb1 + l * DFF + s * 2048, f1_bf, NT, 2048, DM, DM);
      // FF2 TN=64: grid 16x32 = 512 blocks = 2/CU
      k_gemm<false, true, 64><<<dim3(DM / 64, NT / 128), 256, 0, stream>>>(
          f1_bf, fw2 + (size_t)l * DM * DFF + s * 2048,
          s == 0 ? fb2 + l * DM : nullptr, h_bf, NT, DM, 2048, DFF);
    }
  }
  k_logits<<<NT / 4, 256, 0, stream>>>(h_bf, outw, outb, out);
}

// Round 7
// 1839.036 us; speedup vs baseline: 1.0849x; 1.0849x over previous
//
#include <hip/hip_runtime.h>
#include <cstddef>
#include <cstdint>

// Model dims
#define BB   4
#define TS   1024
#define DM   1024
#define DFF  4096
#define NHD  16
#define HDM  64
#define NLY  4
#define TOKD 256
#define POSD 768

typedef __bf16 bf16_t;
typedef __bf16 bf16x4 __attribute__((ext_vector_type(4)));
typedef __bf16 bf16x8 __attribute__((ext_vector_type(8)));
typedef float  f32x4  __attribute__((ext_vector_type(4)));

#define GLOAD_LDS16(gp, lp)                                                  \
  __builtin_amdgcn_global_load_lds(                                          \
      (const __attribute__((address_space(1))) void*)(gp),                   \
      (__attribute__((address_space(3))) void*)(lp), 16, 0, 0)

__device__ __forceinline__ float gelu_f(float x) {
  float x3 = x * x * x;
  return 0.5f * x * (1.0f + tanhf(0.7978845608028654f * (x + 0.044715f * x3)));
}

// h[b,t,:] = [tok_emb[x_in[b,t]], pos_emb[t]] -> bf16. 4 elems/thread.
__global__ __launch_bounds__(256) void k_embed(const int* __restrict__ x,
    const float* __restrict__ tok, const float* __restrict__ pos,
    bf16_t* __restrict__ h) {
  int idx = (blockIdx.x * 256 + threadIdx.x) * 4;
  int d  = idx & (DM - 1);
  int bt = idx >> 10;
  int t  = bt & (TS - 1);
  int b  = bt >> 10;
  float4 v;
  if (d < TOKD) {
    int tk = (t == 0) ? 1 : x[b * TS + t - 1];
    v = *(const float4*)(tok + tk * TOKD + d);
  } else {
    v = *(const float4*)(pos + (size_t)t * POSD + (d - TOKD));
  }
  bf16x4 o = { (bf16_t)v.x, (bf16_t)v.y, (bf16_t)v.z, (bf16_t)v.w };
  *(bf16x4*)(h + idx) = o;
}

// LayerNorm, one wave per 1024-dim row, bf16 in, bf16 out(s) (either may be
// null). fp32 statistics. Lane owns 16 contiguous elems.
__global__ __launch_bounds__(256) void k_ln(const bf16_t* __restrict__ in,
    const float* __restrict__ g, const float* __restrict__ bta,
    bf16_t* __restrict__ out1, bf16_t* __restrict__ out2) {
  int row  = blockIdx.x * 4 + (threadIdx.x >> 6);
  int lane = threadIdx.x & 63;
  const bf16_t* p = in + (size_t)row * DM + lane * 16;
  bf16x8 v0 = *(const bf16x8*)p;
  bf16x8 v1 = *(const bf16x8*)(p + 8);
  float vals[16];
  float s = 0.f, s2 = 0.f;
#pragma unroll
  for (int i = 0; i < 8; i++) { vals[i] = (float)v0[i]; vals[8 + i] = (float)v1[i]; }
#pragma unroll
  for (int i = 0; i < 16; i++) { s += vals[i]; s2 += vals[i] * vals[i]; }
#pragma unroll
  for (int off = 32; off; off >>= 1) {
    s  += __shfl_xor(s, off);
    s2 += __shfl_xor(s2, off);
  }
  float mu  = s * (1.f / DM);
  float var = s2 * (1.f / DM) - mu * mu;
  float rs  = rsqrtf(var + 1e-5f);
  bf16x8 o0, o1;
#pragma unroll
  for (int i = 0; i < 16; i++) {
    int d = lane * 16 + i;
    float v = (vals[i] - mu) * rs * g[d] + bta[d];
    if (i < 8) o0[i] = (bf16_t)v; else o1[i - 8] = (bf16_t)v;
  }
  size_t off = (size_t)row * DM + lane * 16;
  if (out1) { *(bf16x8*)(out1 + off) = o0; *(bf16x8*)(out1 + off + 8) = o1; }
  if (out2) { *(bf16x8*)(out2 + off) = o0; *(bf16x8*)(out2 + off + 8) = o1; }
}

// MFMA bf16 GEMM: C[M,N] = epi(A[M,K] * B[N,K]^T + bias[N])
// A: bf16, row stride K, staged via global_load_lds w=16.
// B: fp32 weights, row stride ldb, staged+converted to bf16 in LDS.
// C: bf16, row stride N. ACC: C += (read-modify-write, bf16 round).
// TMxTN tile / 256 threads / 4 waves (2x2 of (TM/2)x(TN/2)), BK=32.
// TM=TN=64 everywhere: grid 4-8 blocks/CU. Rounds 1-2 established the
// GEMMs are latency-bound with TLP as the hiding mechanism (1->2
// blocks/CU gave +16% with occupancy tracking prediction); this doubles
// blocks/CU again. LDS 16KB/block (cap 10/CU), VGPR ~48 -> grid-limited.
//
// 2-phase double-buffered pipeline (round-2 known-good structure):
//   per iter t: issue A-DMA + B-reg-loads for tile t+1 into buf p^1,
//   compute tile t, commit B(t+1) to LDS, ONE __syncthreads, swap.
template <bool GELU, bool ACC, int TM, int TN>
__global__ __launch_bounds__(256) void k_gemm(
    const bf16_t* __restrict__ A, const float* __restrict__ B,
    const float* __restrict__ bias, bf16_t* __restrict__ C,
    int M, int N, int K, int ldb) {
  constexpr int MI = TM / 32;          // m-frags per wave (2 @ TM=64)
  constexpr int NJ = TN / 32;          // n-frags per wave (2 @ TN=64)
  __shared__ __align__(16) bf16_t As[2][TM * 32];
  __shared__ __align__(16) bf16_t Bs[2][TN * 32];
  const int tid  = threadIdx.x;
  const int wave = tid >> 6, lane = tid & 63;
  const int m0 = blockIdx.y * TM, n0 = blockIdx.x * TN;
  const int wm = (wave >> 1) * (TM / 2), wn = (wave & 1) * (TN / 2);
  f32x4 acc[MI][NJ];
#pragma unroll
  for (int i = 0; i < MI; i++)
#pragma unroll
    for (int j = 0; j < NJ; j++) acc[i][j] = {0.f, 0.f, 0.f, 0.f};

  // A staging: wave owns 16 rows/issue (TM=64 -> 1 issue, TM=128 -> 2)
  const int srow = wave * 16 + (lane >> 2);
  const int scol = (lane & 3) * 8;
  const bf16_t* Ag = A + (size_t)(m0 + srow) * K + scol;
  const int aw0 = wave * 16 * 32;
  // B staging (fp32 -> bf16): thread covers rows {tid>>3 + 32i}, 4 cols
  const int brow = tid >> 3;
  const int bcol = (tid & 7) * 4;
  const float* Bg = B + (size_t)(n0 + brow) * ldb + bcol;
  const int fr = lane & 15, fq = lane >> 4;
  const int nt = K >> 5;

  float4 breg[NJ];
  // ---- prologue: stage tile 0 into buf 0 ----
  GLOAD_LDS16(Ag, &As[0][aw0]);
  if (TM > 64) GLOAD_LDS16(Ag + (size_t)64 * K, &As[0][aw0 + 64 * 32]);
#pragma unroll
  for (int i = 0; i < NJ; i++)
    breg[i] = *(const float4*)(Bg + (size_t)(i * 32) * ldb);
#pragma unroll
  for (int i = 0; i < NJ; i++) {
    bf16x4 o = { (bf16_t)breg[i].x, (bf16_t)breg[i].y,
                 (bf16_t)breg[i].z, (bf16_t)breg[i].w };
    *(bf16x4*)&Bs[0][(brow + i * 32) * 32 + bcol] = o;
  }
  __syncthreads();   // drains A-DMA (vmcnt) + B ds_write (lgkmcnt)

  int p = 0;
  for (int t = 0; t < nt; t++, p ^= 1) {
    const bool more = (t + 1 < nt);
    const int k1 = (t + 1) << 5;
    // ---- issue next tile's global traffic (fire-and-forget) ----
    if (more) {
      GLOAD_LDS16(Ag + k1, &As[p ^ 1][aw0]);
      if (TM > 64)
        GLOAD_LDS16(Ag + (size_t)64 * K + k1, &As[p ^ 1][aw0 + 64 * 32]);
#pragma unroll
      for (int i = 0; i < NJ; i++)
        breg[i] = *(const float4*)(Bg + (size_t)(i * 32) * ldb + k1);
    }
    // ---- compute current tile ----
    bf16x8 af[MI], bfv[NJ];
#pragma unroll
    for (int i = 0; i < MI; i++)
      af[i] = *(const bf16x8*)&As[p][(wm + i * 16 + fr) * 32 + fq * 8];
#pragma unroll
    for (int j = 0; j < NJ; j++)
      bfv[j] = *(const bf16x8*)&Bs[p][(wn + j * 16 + fr) * 32 + fq * 8];
#pragma unroll
    for (int i = 0; i < MI; i++)
#pragma unroll
      for (int j = 0; j < NJ; j++)
        acc[i][j] = __builtin_amdgcn_mfma_f32_16x16x32_bf16(
            af[i], bfv[j], acc[i][j], 0, 0, 0);
    // ---- commit next tile's B (waits vmcnt internally), one barrier ----
    if (more) {
#pragma unroll
      for (int i = 0; i < NJ; i++) {
        bf16x4 o = { (bf16_t)breg[i].x, (bf16_t)breg[i].y,
                     (bf16_t)breg[i].z, (bf16_t)breg[i].w };
        *(bf16x4*)&Bs[p ^ 1][(brow + i * 32) * 32 + bcol] = o;
      }
    }
    __syncthreads();   // drains A-DMA for t+1 + B ds_write; swap is safe
  }
  // epilogue: C/D layout col = lane&15, row = (lane>>4)*4 + reg  [m89]
#pragma unroll
  for (int i = 0; i < MI; i++) {
#pragma unroll
    for (int j = 0; j < NJ; j++) {
#pragma unroll
      for (int r = 0; r < 4; r++) {
        int m = m0 + wm + i * 16 + fq * 4 + r;
        int n = n0 + wn + j * 16 + fr;
        float v = acc[i][j][r];
        if (bias) v += bias[n];
        if (GELU) v = gelu_f(v);
        size_t off = (size_t)m * N + n;
        if (ACC) C[off] = (bf16_t)((float)C[off] + v);
        else     C[off] = (bf16_t)v;
      }
    }
  }
}

// MFMA flash attention. qkv bf16 [2*TS, 3*DM] (2 batches); hres (bf16) += attn.
// Grid (head, q-tile, batch-in-group). Wave w owns q-rows w*16..+15.
// Per 64-wide K-tile: QK^T (8 mfma/wave), online softmax in C-layout regs,
// P->bf16 via LDS (C->A layout round trip), PV (8 mfma/wave). V staged
// transposed. LDS stride 72 breaks bank degeneracy.
__global__ __launch_bounds__(256) void k_flash(const bf16_t* __restrict__ qkv,
                                               bf16_t* __restrict__ hres) {
  __shared__ __align__(16) bf16_t Qs[64 * 72];   // re-used as P after Q->regs
  __shared__ __align__(16) bf16_t Ks[64 * 72];
  __shared__ __align__(16) bf16_t Vt[64 * 72];   // [dim][s]
  const int hh = blockIdx.x, qt = blockIdx.y, bz = blockIdx.z;
  const int tid = threadIdx.x;
  const int w = tid >> 6, lane = tid & 63;
  const int fr = lane & 15, fq = lane >> 4;
  const int sr = tid >> 2, seg = tid & 3;
  const bf16_t* base = qkv + (size_t)bz * TS * (3 * DM) + hh * HDM;
  bf16_t* Ps = Qs;

  {
    const bf16_t* qrow = base + (size_t)(qt * 64 + sr) * (3 * DM) + seg * 16;
    *(bf16x8*)&Qs[sr * 72 + seg * 16]     = *(const bf16x8*)qrow;
    *(bf16x8*)&Qs[sr * 72 + seg * 16 + 8] = *(const bf16x8*)(qrow + 8);
  }
  __syncthreads();
  bf16x8 aq[2];
  aq[0] = *(const bf16x8*)&Qs[(w * 16 + fr) * 72 + fq * 8];
  aq[1] = *(const bf16x8*)&Qs[(w * 16 + fr) * 72 + 32 + fq * 8];

  f32x4 o[4];
#pragma unroll
  for (int d = 0; d < 4; d++) o[d] = {0.f, 0.f, 0.f, 0.f};
  float mval[4] = {-1e30f, -1e30f, -1e30f, -1e30f};
  float lsum[4] = {0.f, 0.f, 0.f, 0.f};

  for (int st = 0; st <= qt; st++) {
    __syncthreads();
    {
      size_t rowoff = (size_t)(st * 64 + sr) * (3 * DM);
      const bf16_t* krow = base + rowoff + DM + seg * 16;
      *(bf16x8*)&Ks[sr * 72 + seg * 16]     = *(const bf16x8*)krow;
      *(bf16x8*)&Ks[sr * 72 + seg * 16 + 8] = *(const bf16x8*)(krow + 8);
      const bf16_t* vrow = base + rowoff + 2 * DM + seg * 16;
      bf16x8 v0 = *(const bf16x8*)vrow;
      bf16x8 v1 = *(const bf16x8*)(vrow + 8);
#pragma unroll
      for (int j = 0; j < 8; j++) Vt[(seg * 16 + j) * 72 + sr]     = v0[j];
#pragma unroll
      for (int j = 0; j < 8; j++) Vt[(seg * 16 + 8 + j) * 72 + sr] = v1[j];
    }
    __syncthreads();
    f32x4 sacc[4];
#pragma unroll
    for (int j = 0; j < 4; j++) sacc[j] = {0.f, 0.f, 0.f, 0.f};
#pragma unroll
    for (int j = 0; j < 4; j++)
#pragma unroll
      for (int hf = 0; hf < 2; hf++) {
        bf16x8 bk = *(const bf16x8*)&Ks[(j * 16 + fr) * 72 + hf * 32 + fq * 8];
        sacc[j] = __builtin_amdgcn_mfma_f32_16x16x32_bf16(aq[hf], bk, sacc[j],
                                                          0, 0, 0);
      }
#pragma unroll
    for (int j = 0; j < 4; j++)
#pragma unroll
      for (int r = 0; r < 4; r++) {
        float s = sacc[j][r] * 0.125f;
        if (st == qt && (j * 16 + fr) > (w * 16 + fq * 4 + r)) s = -1e30f;
        sacc[j][r] = s;
      }
    float corr[4];
#pragma unroll
    for (int r = 0; r < 4; r++) {
      float v = fmaxf(fmaxf(sacc[0][r], sacc[1][r]),
                      fmaxf(sacc[2][r], sacc[3][r]));
      v = fmaxf(v, __shfl_xor(v, 1));
      v = fmaxf(v, __shfl_xor(v, 2));
      v = fmaxf(v, __shfl_xor(v, 4));
      v = fmaxf(v, __shfl_xor(v, 8));
      float mn = fmaxf(mval[r], v);
      corr[r] = __expf(mval[r] - mn);
      mval[r] = mn;
      lsum[r] *= corr[r];
    }
#pragma unroll
    for (int d = 0; d < 4; d++)
#pragma unroll
      for (int r = 0; r < 4; r++) o[d][r] *= corr[r];
    float rsum[4] = {0.f, 0.f, 0.f, 0.f};
#pragma unroll
    for (int j = 0; j < 4; j++)
#pragma unroll
      for (int r = 0; r < 4; r++) {
        float p = __expf(sacc[j][r] - mval[r]);
        rsum[r] += p;
        Ps[(w * 16 + fq * 4 + r) * 72 + j * 16 + fr] = (bf16_t)p;
      }
#pragma unroll
    for (int r = 0; r < 4; r++) {
      float v = rsum[r];
      v += __shfl_xor(v, 1);
      v += __shfl_xor(v, 2);
      v += __shfl_xor(v, 4);
      v += __shfl_xor(v, 8);
      lsum[r] += v;
    }
    __syncthreads();
    bf16x8 ap[2];
    ap[0] = *(const bf16x8*)&Ps[(w * 16 + fr) * 72 + fq * 8];
    ap[1] = *(const bf16x8*)&Ps[(w * 16 + fr) * 72 + 32 + fq * 8];
#pragma unroll
    for (int d = 0; d < 4; d++)
#pragma unroll
      for (int hf = 0; hf < 2; hf++) {
        bf16x8 bv = *(const bf16x8*)&Vt[(d * 16 + fr) * 72 + hf * 32 + fq * 8];
        o[d] = __builtin_amdgcn_mfma_f32_16x16x32_bf16(ap[hf], bv, o[d],
                                                       0, 0, 0);
      }
  }
#pragma unroll
  for (int r = 0; r < 4; r++) {
    float inv = 1.0f / lsum[r];
    bf16_t* row = hres + (size_t)bz * TS * DM +
                  (size_t)(qt * 64 + w * 16 + fq * 4 + r) * DM + hh * HDM;
#pragma unroll
    for (int d = 0; d < 4; d++) {
      int c = d * 16 + fr;
      row[c] = (bf16_t)((float)row[c] + o[d][r] * inv);
    }
  }
}

// logits (M=2) + log_softmax, one wave per token row, bf16 h
__global__ __launch_bounds__(256) void k_logits(const bf16_t* __restrict__ h,
    const float* __restrict__ w, const float* __restrict__ bz,
    float* __restrict__ out) {
  int row  = blockIdx.x * 4 + (threadIdx.x >> 6);
  int lane = threadIdx.x & 63;
  const bf16_t* hp = h + (size_t)row * DM + lane * 16;
  bf16x8 a0 = *(const bf16x8*)hp;
  bf16x8 a1 = *(const bf16x8*)(hp + 8);
  float s0 = 0.f, s1 = 0.f;
#pragma unroll
  for (int i = 0; i < 16; i++) {
    float v = (float)(i < 8 ? a0[i] : a1[i - 8]);
    int d = lane * 16 + i;
    s0 += v * w[d];
    s1 += v * w[DM + d];
  }
#pragma unroll
  for (int off = 32; off; off >>= 1) {
    s0 += __shfl_xor(s0, off);
    s1 += __shfl_xor(s1, off);
  }
  if (lane == 0) {
    float z0 = s0 + bz[0], z1 = s1 + bz[1];
    float mx  = fmaxf(z0, z1);
    float lse = mx + logf(expf(z0 - mx) + expf(z1 - mx));
    out[row * 2]     = z0 - lse;
    out[row * 2 + 1] = z1 - lse;
  }
}

extern "C" void kernel_launch(void* const* d_in, const int* in_sizes, int n_in,
                              void* d_out, int out_size, void* d_ws, size_t ws_size,
                              hipStream_t stream) {
  const int*   x     = (const int*)d_in[0];
  const float* tokE  = (const float*)d_in[1];
  const float* posE  = (const float*)d_in[2];
  const float* w_qkv = (const float*)d_in[3];
  const float* b_qkv = (const float*)d_in[4];
  const float* ln1g  = (const float*)d_in[5];
  const float* ln1b  = (const float*)d_in[6];
  const float* ln2g  = (const float*)d_in[7];
  const float* ln2b  = (const float*)d_in[8];
  const float* fw1   = (const float*)d_in[9];
  const float* fb1   = (const float*)d_in[10];
  const float* fw2   = (const float*)d_in[11];
  const float* fb2   = (const float*)d_in[12];
  const float* outw  = (const float*)d_in[13];
  const float* outb  = (const float*)d_in[14];
  float* out = (float*)d_out;

  const size_t NT = (size_t)BB * TS;  // 4096 tokens
  const size_t MB = 1024 * 1024;
  // Workspace: 32 MB total.
  //   h_bf  [0, 8M):  bf16 residual stream [4096, 1024]
  //   S = [8M, 32M) 24 MB, time-shared:
  //     attn phase (per 2-batch group): a_bf [0,4M) | qkv_bf [4M,16M)
  //     ff phase: a2_bf [0,8M) pristine LN2 | f1_bf [8M,24M) (slab 2048)
  bf16_t* h_bf = (bf16_t*)d_ws;
  char*   S    = (char*)d_ws + 8 * MB;
  bf16_t* a_bf   = (bf16_t*)S;
  bf16_t* qkv_bf = (bf16_t*)(S + 4 * MB);
  bf16_t* a2_bf  = (bf16_t*)S;
  bf16_t* f1_bf  = (bf16_t*)(S + 8 * MB);

  k_embed<<<(NT * DM) / 1024, 256, 0, stream>>>(x, tokE, posE, h_bf);
  for (int l = 0; l < NLY; l++) {
    // --- attention, 2-batch groups (M=2048 QKV GEMM) ---
    for (int g = 0; g < 2; g++) {
      bf16_t* hg = h_bf + (size_t)g * 2 * TS * DM;
      k_ln<<<2 * TS / 4, 256, 0, stream>>>(hg, ln1g + l * DM, ln1b + l * DM,
                                           a_bf, nullptr);
      // 64x64: grid 48x32 = 1536 blocks = 6/CU
      k_gemm<false, false, 64, 64><<<dim3(3 * DM / 64, 2 * TS / 64), 256, 0,
                                     stream>>>(
          a_bf, w_qkv + (size_t)l * 3 * DM * DM, b_qkv + l * 3 * DM, qkv_bf,
          2 * TS, 3 * DM, DM, DM);
      k_flash<<<dim3(NHD, TS / 64, 2), 256, 0, stream>>>(qkv_bf, hg);
    }
    // --- ln2: in-place into h_bf (residual basis) + pristine copy a2_bf ---
    k_ln<<<NT / 4, 256, 0, stream>>>(h_bf, ln2g + l * DM, ln2b + l * DM,
                                     h_bf, a2_bf);
    // --- FF: 2 slabs of 2048 over DFF; FF1 reads pristine a2_bf,
    //     FF2 accumulates into h_bf (bias on slab 0 only) ---
    for (int s = 0; s < 2; s++) {
      // FF1 64x64: grid 32x64 = 2048 blocks = 8/CU
      k_gemm<true, false, 64, 64><<<dim3(2048 / 64, NT / 64), 256, 0, stream>>>(
          a2_bf, fw1 + (size_t)l * DFF * DM + (size_t)s * 2048 * DM,
          fb1 + l * DFF + s * 2048, f1_bf, NT, 2048, DM, DM);
      // FF2 64x64: grid 16x64 = 1024 blocks = 4/CU
      k_gemm<false, true, 64, 64><<<dim3(DM / 64, NT / 64), 256, 0, stream>>>(
          f1_bf, fw2 + (size_t)l * DM * DFF + s * 2048,
          s == 0 ? fb2 + l * DM : nullptr, h_bf, NT, DM, 2048, DFF);
    }
  }
  k_logits<<<NT / 4, 256, 0, stream>>>(h_bf, outw, outb, out);
}